// Round 1
// baseline (418.721 us; speedup 1.0000x reference)
//
#include <hip/hip_runtime.h>

#define G 10
#define NLEV_MINUS_1 255.0f

__global__ __launch_bounds__(256) void madq_kernel(
    const float* __restrict__ x,
    const float* __restrict__ medians,
    const float* __restrict__ deltas,
    const float* __restrict__ zps,
    float* __restrict__ out,
    int n4)
{
    int idx = blockIdx.x * blockDim.x + threadIdx.x;
    if (idx >= n4) return;

    // Table pointers are wave-uniform kernel args with constant indices ->
    // compiler emits s_load; values live in SGPRs.
    float m[G], dd[G], zz[G];
#pragma unroll
    for (int i = 0; i < G; ++i) {
        m[i]  = medians[i];
        dd[i] = deltas[i];
        zz[i] = zps[i];
    }

    const float4* x4 = (const float4*)x;
    float4*       o4 = (float4*)out;
    float4 v = x4[idx];

    float in[4] = {v.x, v.y, v.z, v.w};
    float ou[4];
#pragma unroll
    for (int e = 0; e < 4; ++e) {
        float xv = in[e];
        float xa = fabsf(xv);
        // grp = clip(#{i : |x| >= m[i]}, 0, G-1). Medians sorted ascending,
        // so conditions are monotone: select chain == indexed lookup.
        float d  = dd[0];
        float zp = zz[0];
#pragma unroll
        for (int i = 1; i < G; ++i) {
            bool c = xa >= m[i - 1];
            d  = c ? dd[i] : d;
            zp = c ? zz[i] : zp;
        }
        // rintf = round-half-to-even, matches np.round; precise IEEE divide.
        float q = rintf(xv / d) + zp;
        q = fminf(fmaxf(q, 0.0f), NLEV_MINUS_1);
        ou[e] = (q - zp) * d;
    }
    o4[idx] = make_float4(ou[0], ou[1], ou[2], ou[3]);
}

extern "C" void kernel_launch(void* const* d_in, const int* in_sizes, int n_in,
                              void* d_out, int out_size, void* d_ws, size_t ws_size,
                              hipStream_t stream) {
    const float* x       = (const float*)d_in[0];
    const float* medians = (const float*)d_in[1];
    const float* deltas  = (const float*)d_in[2];
    const float* zps     = (const float*)d_in[3];
    float*       out     = (float*)d_out;

    int n  = in_sizes[0];        // 4*4096*4096, divisible by 4
    int n4 = n / 4;
    const int block = 256;
    int grid = (n4 + block - 1) / block;
    madq_kernel<<<grid, block, 0, stream>>>(x, medians, deltas, zps, out, n4);
}